// Round 4
// baseline (182.916 us; speedup 1.0000x reference)
//
#include <hip/hip_runtime.h>
#include <hip/hip_bf16.h>

// Problem constants (GCNLayer_13357348290889): B=4, N=50000, CIN=64, HALF=32.
#define B_    4
#define N_    50000
#define CIN_  64
#define HALF_ 32
#define NFB_  196      // fill blocks: ceil(E / FILL_T)
#define FILL_T 4096    // edges per fill block
#define SB_   1563     // sort buckets of 32 rows: fb = row >> 5
#define SCAP_ 768      // records per bucket (mean 512, sd 23 -> +11 sigma)
#define TBLK_ 782      // transform blocks (200000 nodes / 256)

typedef __attribute__((ext_vector_type(8))) short bf16x8;   // MFMA A/B frag
typedef __attribute__((ext_vector_type(4))) float f32x4;    // MFMA C/D frag

// fp32 -> bf16 round-to-nearest-even (inputs are finite normals)
static __device__ __forceinline__ unsigned short f2bf(float f) {
    unsigned u = __float_as_uint(f);
    return (unsigned short)((u + 0x7FFFu + ((u >> 16) & 1u)) >> 16);
}

// pack 8 consecutive f32 -> bf16x8 (RNE via v_cvt_pk_bf16_f32)
static __device__ __forceinline__ bf16x8 pack8(float4 a, float4 b) {
    union { __hip_bfloat162 h[4]; bf16x8 v; } u;
    u.h[0] = __float22bfloat162_rn(make_float2(a.x, a.y));
    u.h[1] = __float22bfloat162_rn(make_float2(a.z, a.w));
    u.h[2] = __float22bfloat162_rn(make_float2(b.x, b.y));
    u.h[3] = __float22bfloat162_rn(make_float2(b.z, b.w));
    return u.v;
}

// ---------------------------------------------------------------------------
// mega1: grid-fused transform (blocks NFB_..NFB_+781) + fill (blocks 0..195).
//
// R4: transform rebuilt on MFMA (was LDS-pipe-bound: 512 ds_read_b128/block
// for 64 FMA/thread; R3 showed conflicts/LDS-size fixes didn't move time).
// D = W · X^T with mfma_f32_16x16x32_bf16:
//   A-frag: lane = W[otile*16 + (l&15)][(l>>4)*8 + j]   (16B contiguous, L2)
//   B-frag: lane = x[node0 + (l&15)][(l>>4)*8 + j]      (16B contiguous)
//   D (verified m89): col=lane&15 -> node, row=(lane>>4)*4+reg -> 4
//   consecutive output channels -> direct ushort4 / float4 stores.
// Zero LDS in transform; K=64 via 2 chained MFMAs; 64 nodes per wave.
// fill: bin edges into 1563 buckets (32 rows). Record: int2(col|row<<16, val).
// ---------------------------------------------------------------------------
__global__ __launch_bounds__(256) void mega1_kernel(
    const float* __restrict__ x,
    const float* __restrict__ Wlin,
    const float* __restrict__ Weye, const float* __restrict__ beye,
    unsigned short* __restrict__ y, float* __restrict__ out,
    const int* __restrict__ rows, const int* __restrict__ cols,
    const float* __restrict__ vals,
    int* __restrict__ cbcursor, int2* __restrict__ sEdge1, int E)
{
    __shared__ int hist[SB_], res[SB_], lcur[SB_];   // fill-branch only (18.8 KB)
    int t = threadIdx.x;

    if (blockIdx.x < NFB_) {
        // ---------------- fill part ----------------
        for (int i = t; i < SB_; i += 256) hist[i] = 0;
        __syncthreads();

        int e0   = blockIdx.x * FILL_T;
        int eEnd = e0 + FILL_T; if (eEnd > E) eEnd = E;

        for (int e = e0 + t; e < eEnd; e += 256)
            atomicAdd(&hist[((unsigned)rows[e]) >> 5], 1);
        __syncthreads();

        for (int i = t; i < SB_; i += 256) {
            int h = hist[i];
            res[i]  = h ? atomicAdd(&cbcursor[i], h) : 0;
            lcur[i] = 0;
        }
        __syncthreads();

        for (int e = e0 + t; e < eEnd; e += 256) {
            unsigned r = (unsigned)rows[e];
            int fb = r >> 5;
            int p  = res[fb] + atomicAdd(&lcur[fb], 1);
            if (p < SCAP_)
                sEdge1[(size_t)fb * SCAP_ + p] =
                    make_int2((int)(((unsigned)cols[e]) | (r << 16)),
                              __float_as_int(vals[e]));
        }
        return;
    }

    // ---------------- transform part (MFMA, no LDS) ----------------
    int tb   = blockIdx.x - NFB_;                  // 0..781
    int wv   = t >> 6, lane = t & 63;
    int lm   = lane & 15;                          // node-in-mtile / W-row-in-otile
    int lg   = lane >> 4;                          // lane group 0..3 (k-chunk)
    int nodeW = tb * 256 + wv * 64;                // wave's 64 nodes
    if (nodeW >= B_ * N_) return;

    // A-operand: W fragments, otile u (16 outputs), k-half h (32 cin)
    bf16x8 wf[8];
#pragma unroll
    for (int u = 0; u < 4; ++u) {
        const float* wrow = (u < 2) ? (Wlin + (u * 16 + lm) * 64)
                                    : (Weye + ((u - 2) * 16 + lm) * 64);
#pragma unroll
        for (int h = 0; h < 2; ++h) {
            const float* wp = wrow + h * 32 + lg * 8;
            wf[u * 2 + h] = pack8(*(const float4*)wp, *(const float4*)(wp + 4));
        }
    }
    float4 be0 = ((const float4*)beye)[lg];        // otile 2 bias (4 ch)
    float4 be1 = ((const float4*)beye)[4 + lg];    // otile 3 bias

    ushort4* y4  = (ushort4*)y;
    float4*  out4 = (float4*)out;

#pragma unroll
    for (int m = 0; m < 4; ++m) {
        int node0 = nodeW + m * 16;
        const float* xp = x + (size_t)(node0 + lm) * 64 + lg * 8;
        bf16x8 xf0 = pack8(*(const float4*)xp,        *(const float4*)(xp + 4));
        bf16x8 xf1 = pack8(*(const float4*)(xp + 32), *(const float4*)(xp + 36));

        int flat = node0 + lm;                     // this lane's output node
        int b    = flat / N_;
        int nn   = flat - b * N_;

#pragma unroll
        for (int u = 0; u < 4; ++u) {
            f32x4 acc = {0.f, 0.f, 0.f, 0.f};
            acc = __builtin_amdgcn_mfma_f32_16x16x32_bf16(wf[u*2+0], xf0, acc, 0, 0, 0);
            acc = __builtin_amdgcn_mfma_f32_16x16x32_bf16(wf[u*2+1], xf1, acc, 0, 0, 0);
            if (u < 2) {                           // lin -> y bf16 [n][b][32]
                ushort4 pk;
                pk.x = f2bf(acc[0]); pk.y = f2bf(acc[1]);
                pk.z = f2bf(acc[2]); pk.w = f2bf(acc[3]);
                y4[(size_t)nn * 32 + b * 8 + u * 4 + lg] = pk;
            } else {                               // eye -> out[:,32:64] + bias
                float4 be = (u == 2) ? be0 : be1;
                out4[(size_t)flat * 16 + 8 + (u - 2) * 4 + lg] =
                    make_float4(acc[0] + be.x, acc[1] + be.y,
                                acc[2] + be.z, acc[3] + be.w);
            }
        }
    }
}

// ---------------------------------------------------------------------------
// sortgather: one 256-thread block (4 waves) per 32-row bucket (R4: finer
// buckets, 1563 blocks -> ~24 waves/CU of work; was 12). Phase A: cache <=3
// records/thread in registers + LDS row histogram. Phase B: 32-bin shfl scan.
// Phase C: scatter 4B records (bf16 val | col) into LDS. Phase D: 4 waves x
// 8 rows; per edge one coalesced yu dword per lane, register accumulate.
// out[b,n,0:32] = b_lin + sum. No f32 atomics.
// ---------------------------------------------------------------------------
__global__ __launch_bounds__(256) void sortgather_kernel(
    const int2* __restrict__ sEdge1, const int* __restrict__ cbcursor,
    const unsigned int* __restrict__ yu, const float* __restrict__ blin,
    float* __restrict__ out)
{
    __shared__ int hist[32], cur[32], rs_s[32], rs_e[32];
    __shared__ unsigned int sorted[SCAP_];         // 3 KB

    int t = threadIdx.x, fb = blockIdx.x;
    int cnt = cbcursor[fb]; if (cnt > SCAP_) cnt = SCAP_;
    const int2* src = sEdge1 + (size_t)fb * SCAP_;

    if (t < 32) hist[t] = 0;
    __syncthreads();

    // Phase A: register-cache records (static indexing) + histogram
    int2 rc[3];
#pragma unroll
    for (int u = 0; u < 3; ++u) {
        int i = t + 256 * u;
        if (i < cnt) {
            rc[u] = src[i];
            atomicAdd(&hist[(((unsigned)rc[u].x) >> 16) & 31u], 1);
        }
    }
    __syncthreads();

    // Phase B: 32-bin inclusive scan in wave 0 (5 shfl steps)
    if (t < 32) {
        int v = hist[t], s = v;
#pragma unroll
        for (int d = 1; d < 32; d <<= 1) {
            int tv = __shfl_up(s, d, 64);
            if (t >= d) s += tv;
        }
        cur[t] = s - v; rs_s[t] = s - v; rs_e[t] = s;
    }
    __syncthreads();

    // Phase C: scatter from registers into row-grouped LDS
#pragma unroll
    for (int u = 0; u < 3; ++u) {
        int i = t + 256 * u;
        if (i < cnt) {
            int2 w = rc[u];
            int rl = (((unsigned)w.x) >> 16) & 31;
            int p  = atomicAdd(&cur[rl], 1);
            sorted[p] = ((unsigned)f2bf(__int_as_float(w.y)) << 16)
                      | (((unsigned)w.x) & 0xFFFFu);
        }
    }
    __syncthreads();

    // Phase D: gather
    int wv = t >> 6, lane = t & 63;
    int b  = lane >> 4;
    int c0 = (lane & 15) * 2;
    float bl0 = blin[c0], bl1 = blin[c0 + 1];

    for (int r = wv * 8; r < wv * 8 + 8; ++r) {
        int n = fb * 32 + r;
        if (n >= N_) break;
        int st = rs_s[r], en = rs_e[r];
        float a0 = 0.f, a1 = 0.f;
        for (int j = st; j < en; j += 8) {
            unsigned rec[8];
#pragma unroll
            for (int u = 0; u < 8; ++u) {
                int idx = j + u;
                unsigned rr = sorted[idx < en ? idx : en - 1];
                if (idx >= en) rr &= 0xFFFFu;      // zero val -> exact no-op
                rec[u] = rr;
            }
            unsigned w4[8];
#pragma unroll
            for (int u = 0; u < 8; ++u)
                w4[u] = yu[(size_t)(rec[u] & 0xFFFFu) * 64 + lane];
#pragma unroll
            for (int u = 0; u < 8; ++u) {
                float vv = __uint_as_float(rec[u] & 0xFFFF0000u);
                a0 = fmaf(vv, __uint_as_float(w4[u] << 16), a0);
                a1 = fmaf(vv, __uint_as_float(w4[u] & 0xFFFF0000u), a1);
            }
        }
        float2 rr2;
        rr2.x = bl0 + a0;
        rr2.y = bl1 + a1;
        *(float2*)&out[((size_t)b * N_ + n) * 64 + c0] = rr2;
    }
}

// ---------------------------------------------------------------------------
// Fallback (tiny ws): atomic scatter at 64 ch + in-place transform.
// ---------------------------------------------------------------------------
__global__ __launch_bounds__(256) void scatter64_kernel(
    const float* __restrict__ x, const float* __restrict__ vals,
    const int* __restrict__ rows, const int* __restrict__ cols,
    float* __restrict__ out, int E)
{
    int idx = blockIdx.x * 256 + threadIdx.x;
    if (idx >= E * 256) return;
    int c = idx & 63, b = (idx >> 6) & 3, e = idx >> 8;
    atomicAdd(&out[((size_t)b * N_ + rows[e]) * 64 + c],
              vals[e] * x[((size_t)b * N_ + cols[e]) * 64 + c]);
}

__global__ __launch_bounds__(256) void transform_inplace_kernel(
    const float* __restrict__ x,
    const float* __restrict__ Wlin, const float* __restrict__ blin,
    const float* __restrict__ Weye, const float* __restrict__ beye,
    float* __restrict__ out, int total_nodes)
{
    __shared__ float Wt[64 * 65];
    __shared__ float bias[64];
    __shared__ float axs[4][64];
    __shared__ float xs2[4][64];
    int tid = threadIdx.x;
    for (int i = tid; i < HALF_ * CIN_; i += 256) {
        int o = i >> 6, c = i & 63;
        Wt[c * 65 + o]      = Wlin[i];
        Wt[c * 65 + o + 32] = Weye[i];
    }
    if (tid < 32) { bias[tid] = blin[tid]; bias[tid + 32] = beye[tid]; }
    __syncthreads();
    int wave = tid >> 6, lane = tid & 63;
    int node = blockIdx.x * 4 + wave;
    if (node < total_nodes) {
        axs[wave][lane] = out[node * 64 + lane];
        xs2[wave][lane] = x[node * 64 + lane];
    }
    __syncthreads();
    if (node >= total_nodes) return;
    const float* src = (lane < 32) ? axs[wave] : xs2[wave];
    float acc = bias[lane];
#pragma unroll
    for (int c = 0; c < 64; ++c) acc = fmaf(src[c], Wt[c * 65 + lane], acc);
    out[node * 64 + lane] = acc;
}

extern "C" void kernel_launch(void* const* d_in, const int* in_sizes, int n_in,
                              void* d_out, int out_size, void* d_ws, size_t ws_size,
                              hipStream_t stream) {
    const float* x    = (const float*)d_in[0];
    const float* vals = (const float*)d_in[1];
    const float* Wlin = (const float*)d_in[2];
    const float* blin = (const float*)d_in[3];
    const float* Weye = (const float*)d_in[4];
    const float* beye = (const float*)d_in[5];
    const int*   rows = (const int*)d_in[6];
    const int*   cols = (const int*)d_in[7];
    float*       out  = (float*)d_out;

    const int E = in_sizes[1];                       // 800000
    const int total_nodes = B_ * N_;                 // 200000

    // ws layout
    char* base = (char*)d_ws;
    size_t off_y      = 0;
    size_t off_edge1  = off_y     + (size_t)N_ * B_ * HALF_ * 2;   // 12.8 MB
    size_t off_cur    = off_edge1 + (size_t)SB_ * SCAP_ * 8;       // 9.60 MB
    size_t need       = off_cur   + 8192;

    if (ws_size >= need && E <= NFB_ * FILL_T) {
        unsigned short* y      = (unsigned short*)(base + off_y);
        int2*           sEdge1 = (int2*)          (base + off_edge1);
        int*            cbcur  = (int*)           (base + off_cur);

        hipMemsetAsync(cbcur, 0, SB_ * 4, stream);
        mega1_kernel<<<TBLK_ + NFB_, 256, 0, stream>>>(
            x, Wlin, Weye, beye, y, out, rows, cols, vals, cbcur, sEdge1, E);
        sortgather_kernel<<<SB_, 256, 0, stream>>>(
            sEdge1, cbcur, (const unsigned int*)y, blin, out);
    } else {
        hipMemsetAsync(d_out, 0, (size_t)out_size * sizeof(float), stream);
        scatter64_kernel<<<(E * 256 + 255) / 256, 256, 0, stream>>>(
            x, vals, rows, cols, out, E);
        transform_inplace_kernel<<<(total_nodes + 3) / 4, 256, 0, stream>>>(
            x, Wlin, blin, Weye, beye, out, total_nodes);
    }
}

// Round 5
// 181.218 us; speedup vs baseline: 1.0094x; 1.0094x over previous
//
#include <hip/hip_runtime.h>
#include <hip/hip_bf16.h>

// Problem constants (GCNLayer_13357348290889): B=4, N=50000, CIN=64, HALF=32.
#define B_    4
#define N_    50000
#define CIN_  64
#define HALF_ 32
#define NFB_  196      // fill blocks: ceil(E / FILL_T)
#define FILL_T 4096    // edges per fill block
#define SB_   1563     // sort buckets of 32 rows: fb = row >> 5
#define SCAP_ 768      // records per bucket (mean 512, sd 23 -> +11 sigma)
#define TBLK_ 1563     // transform blocks (200000 nodes / 128, rounded up)

typedef __attribute__((ext_vector_type(8))) short bf16x8;   // MFMA A/B frag
typedef __attribute__((ext_vector_type(4))) float f32x4;    // MFMA C/D frag

// fp32 -> bf16 round-to-nearest-even (inputs are finite normals)
static __device__ __forceinline__ unsigned short f2bf(float f) {
    unsigned u = __float_as_uint(f);
    return (unsigned short)((u + 0x7FFFu + ((u >> 16) & 1u)) >> 16);
}

// pack 8 consecutive f32 -> bf16x8 (RNE via v_cvt_pk_bf16_f32)
static __device__ __forceinline__ bf16x8 pack8(float4 a, float4 b) {
    union { __hip_bfloat162 h[4]; bf16x8 v; } u;
    u.h[0] = __float22bfloat162_rn(make_float2(a.x, a.y));
    u.h[1] = __float22bfloat162_rn(make_float2(a.z, a.w));
    u.h[2] = __float22bfloat162_rn(make_float2(b.x, b.y));
    u.h[3] = __float22bfloat162_rn(make_float2(b.z, b.w));
    return u.v;
}

// ---------------------------------------------------------------------------
// mega1: grid-fused transform (blocks NFB_..) + fill (blocks 0..195).
//
// R5 (counter-driven): R4 was latency-bound (VALUBusy 4%, MfmaUtil 1%,
// occupancy 14%, VGPR=68 -> compiler serialized the m-loop's loads).
//  - transform: explicit load-all-then-compute (8 x-loads + 16 W-loads in
//    flight before any pack/MFMA), 128 nodes/block -> grid 1759 (~27
//    waves/CU of work).
//  - fill: single-array cursor trick (hist -> base -> cursor in place):
//    LDS 18.9KB -> 6.3KB per block.
// MFMA D = W · X^T layout (verified m89): col=lane&15 -> node,
// row=(lane>>4)*4+reg -> 4 consecutive out channels per lane.
// ---------------------------------------------------------------------------
__global__ __launch_bounds__(256) void mega1_kernel(
    const float* __restrict__ x,
    const float* __restrict__ Wlin,
    const float* __restrict__ Weye, const float* __restrict__ beye,
    unsigned short* __restrict__ y, float* __restrict__ out,
    const int* __restrict__ rows, const int* __restrict__ cols,
    const float* __restrict__ vals,
    int* __restrict__ cbcursor, int2* __restrict__ sEdge1, int E)
{
    __shared__ int hist[SB_];                      // 6252 B
    int t = threadIdx.x;

    if (blockIdx.x < NFB_) {
        // ---------------- fill part ----------------
        for (int i = t; i < SB_; i += 256) hist[i] = 0;
        __syncthreads();

        int e0   = blockIdx.x * FILL_T;
        int eEnd = e0 + FILL_T; if (eEnd > E) eEnd = E;

        for (int e = e0 + t; e < eEnd; e += 256)
            atomicAdd(&hist[((unsigned)rows[e]) >> 5], 1);
        __syncthreads();

        // exchange: hist[i] becomes this block's global base for bucket i
        for (int i = t; i < SB_; i += 256) {
            int h = hist[i];
            if (h) hist[i] = atomicAdd(&cbcursor[i], h);
        }
        __syncthreads();

        for (int e = e0 + t; e < eEnd; e += 256) {
            unsigned r = (unsigned)rows[e];
            int fb = r >> 5;
            int p  = atomicAdd(&hist[fb], 1);      // global slot directly
            if (p < SCAP_)
                sEdge1[(size_t)fb * SCAP_ + p] =
                    make_int2((int)(((unsigned)cols[e]) | (r << 16)),
                              __float_as_int(vals[e]));
        }
        return;
    }

    // ---------------- transform part (MFMA, no LDS) ----------------
    int tb   = blockIdx.x - NFB_;                  // 0..1562
    int wv   = t >> 6, lane = t & 63;
    int lm   = lane & 15;                          // node-in-mtile / W-row
    int lg   = lane >> 4;                          // k-chunk 0..3
    int nodeW = tb * 128 + wv * 32;                // wave's 32 nodes (2 m-tiles)
    if (nodeW >= B_ * N_) return;                  // 200000 % 32 == 0

    // ---- stage 1: issue ALL loads (x first: HBM; then W: L2-hot) ----
    float4 xr[2][4];
#pragma unroll
    for (int m = 0; m < 2; ++m) {
        const float* xp = x + (size_t)(nodeW + m * 16 + lm) * 64 + lg * 8;
        xr[m][0] = *(const float4*)xp;
        xr[m][1] = *(const float4*)(xp + 4);
        xr[m][2] = *(const float4*)(xp + 32);
        xr[m][3] = *(const float4*)(xp + 36);
    }
    float4 wr[4][2][2];                            // [otile][khalf][pair]
#pragma unroll
    for (int u = 0; u < 4; ++u) {
        const float* wrow = (u < 2) ? (Wlin + (u * 16 + lm) * 64)
                                    : (Weye + ((u - 2) * 16 + lm) * 64);
#pragma unroll
        for (int h = 0; h < 2; ++h) {
            const float* wp = wrow + h * 32 + lg * 8;
            wr[u][h][0] = *(const float4*)wp;
            wr[u][h][1] = *(const float4*)(wp + 4);
        }
    }
    float4 be0 = ((const float4*)beye)[lg];        // otile 2 bias (4 ch)
    float4 be1 = ((const float4*)beye)[4 + lg];    // otile 3 bias

    // ---- stage 2: pack ----
    bf16x8 wf[8];
#pragma unroll
    for (int u = 0; u < 4; ++u)
#pragma unroll
        for (int h = 0; h < 2; ++h)
            wf[u * 2 + h] = pack8(wr[u][h][0], wr[u][h][1]);
    bf16x8 xf[2][2];
#pragma unroll
    for (int m = 0; m < 2; ++m) {
        xf[m][0] = pack8(xr[m][0], xr[m][1]);
        xf[m][1] = pack8(xr[m][2], xr[m][3]);
    }

    // ---- stage 3: MFMA + stores ----
    ushort4* y4   = (ushort4*)y;
    float4*  out4 = (float4*)out;
#pragma unroll
    for (int m = 0; m < 2; ++m) {
        int flat = nodeW + m * 16 + lm;            // this lane's output node
        int b    = flat / N_;
        int nn   = flat - b * N_;
#pragma unroll
        for (int u = 0; u < 4; ++u) {
            f32x4 acc = {0.f, 0.f, 0.f, 0.f};
            acc = __builtin_amdgcn_mfma_f32_16x16x32_bf16(wf[u*2+0], xf[m][0], acc, 0, 0, 0);
            acc = __builtin_amdgcn_mfma_f32_16x16x32_bf16(wf[u*2+1], xf[m][1], acc, 0, 0, 0);
            if (u < 2) {                           // lin -> y bf16 [n][b][32]
                ushort4 pk;
                pk.x = f2bf(acc[0]); pk.y = f2bf(acc[1]);
                pk.z = f2bf(acc[2]); pk.w = f2bf(acc[3]);
                y4[(size_t)nn * 32 + b * 8 + u * 4 + lg] = pk;
            } else {                               // eye -> out[:,32:64] + bias
                float4 be = (u == 2) ? be0 : be1;
                out4[(size_t)flat * 16 + 8 + (u - 2) * 4 + lg] =
                    make_float4(acc[0] + be.x, acc[1] + be.y,
                                acc[2] + be.z, acc[3] + be.w);
            }
        }
    }
}

// ---------------------------------------------------------------------------
// sortgather: one 256-thread block (4 waves) per 32-row bucket.
// Phase A: cache <=3 records/thread in registers + LDS row histogram.
// Phase B: 32-bin shfl scan. Phase C: scatter 4B records into LDS.
// Phase D (R5): records are wave-uniform -> readfirstlane scalarization
// (col/val extraction + yu row address on SALU, saddr loads); full-group /
// clamped-tail loop split (no bounds VALU in main groups); TWO rows
// processed concurrently per iteration -> 16 yu loads in flight per wave.
// out[b,n,0:32] = b_lin + sum. No f32 atomics.
// ---------------------------------------------------------------------------
#define GRP(J, EN, CLAMP, A0, A1) do {                                     \
        unsigned rec_[8];                                                  \
        _Pragma("unroll")                                                  \
        for (int u_ = 0; u_ < 8; ++u_) {                                   \
            int idx_ = (J) + u_;                                           \
            unsigned rr_;                                                  \
            if (CLAMP) {                                                   \
                rr_ = sorted[idx_ < (EN) ? idx_ : (EN) - 1];               \
                if (idx_ >= (EN)) rr_ &= 0xFFFFu;  /* zero val: no-op */   \
            } else {                                                       \
                rr_ = sorted[idx_];                                        \
            }                                                              \
            rec_[u_] = __builtin_amdgcn_readfirstlane(rr_);                \
        }                                                                  \
        unsigned w4_[8];                                                   \
        _Pragma("unroll")                                                  \
        for (int u_ = 0; u_ < 8; ++u_)                                     \
            w4_[u_] = yu[(size_t)(rec_[u_] & 0xFFFFu) * 64 + lane];        \
        _Pragma("unroll")                                                  \
        for (int u_ = 0; u_ < 8; ++u_) {                                   \
            float vv_ = __uint_as_float(rec_[u_] & 0xFFFF0000u);           \
            A0 = fmaf(vv_, __uint_as_float(w4_[u_] << 16), A0);            \
            A1 = fmaf(vv_, __uint_as_float(w4_[u_] & 0xFFFF0000u), A1);    \
        }                                                                  \
    } while (0)

__global__ __launch_bounds__(256) void sortgather_kernel(
    const int2* __restrict__ sEdge1, const int* __restrict__ cbcursor,
    const unsigned int* __restrict__ yu, const float* __restrict__ blin,
    float* __restrict__ out)
{
    __shared__ int hist[32], cur[32], rs_s[32], rs_e[32];
    __shared__ unsigned int sorted[SCAP_];         // 3 KB

    int t = threadIdx.x, fb = blockIdx.x;
    int cnt = cbcursor[fb]; if (cnt > SCAP_) cnt = SCAP_;
    const int2* src = sEdge1 + (size_t)fb * SCAP_;

    if (t < 32) hist[t] = 0;
    __syncthreads();

    // Phase A: register-cache records (static indexing) + histogram
    int2 rc[3];
#pragma unroll
    for (int u = 0; u < 3; ++u) {
        int i = t + 256 * u;
        if (i < cnt) {
            rc[u] = src[i];
            atomicAdd(&hist[(((unsigned)rc[u].x) >> 16) & 31u], 1);
        }
    }
    __syncthreads();

    // Phase B: 32-bin inclusive scan in wave 0 (5 shfl steps)
    if (t < 32) {
        int v = hist[t], s = v;
#pragma unroll
        for (int d = 1; d < 32; d <<= 1) {
            int tv = __shfl_up(s, d, 64);
            if (t >= d) s += tv;
        }
        cur[t] = s - v; rs_s[t] = s - v; rs_e[t] = s;
    }
    __syncthreads();

    // Phase C: scatter from registers into row-grouped LDS
#pragma unroll
    for (int u = 0; u < 3; ++u) {
        int i = t + 256 * u;
        if (i < cnt) {
            int2 w = rc[u];
            int rl = (((unsigned)w.x) >> 16) & 31;
            int p  = atomicAdd(&cur[rl], 1);
            sorted[p] = ((unsigned)f2bf(__int_as_float(w.y)) << 16)
                      | (((unsigned)w.x) & 0xFFFFu);
        }
    }
    __syncthreads();

    // Phase D: gather, two rows in flight per wave
    int wv = t >> 6, lane = t & 63;
    int b  = lane >> 4;
    int c0 = (lane & 15) * 2;
    float bl0 = blin[c0], bl1 = blin[c0 + 1];

    for (int rp = 0; rp < 4; ++rp) {
        int rA = wv * 8 + rp * 2, rB = rA + 1;
        int stA = rs_s[rA], enA = rs_e[rA];
        int stB = rs_s[rB], enB = rs_e[rB];
        int fA = stA + ((enA - stA) & ~7);
        int fB = stB + ((enB - stB) & ~7);
        float a0A = 0.f, a1A = 0.f, a0B = 0.f, a1B = 0.f;
        int jA = stA, jB = stB;
        while (jA < fA && jB < fB) {               // dual-row: 16 loads in flight
            GRP(jA, enA, false, a0A, a1A); jA += 8;
            GRP(jB, enB, false, a0B, a1B); jB += 8;
        }
        while (jA < fA) { GRP(jA, enA, false, a0A, a1A); jA += 8; }
        while (jB < fB) { GRP(jB, enB, false, a0B, a1B); jB += 8; }
        if (jA < enA) GRP(jA, enA, true, a0A, a1A);
        if (jB < enB) GRP(jB, enB, true, a0B, a1B);

        int nA = fb * 32 + rA, nB = fb * 32 + rB;
        if (nA < N_) {
            float2 r2; r2.x = bl0 + a0A; r2.y = bl1 + a1A;
            *(float2*)&out[((size_t)b * N_ + nA) * 64 + c0] = r2;
        }
        if (nB < N_) {
            float2 r2; r2.x = bl0 + a0B; r2.y = bl1 + a1B;
            *(float2*)&out[((size_t)b * N_ + nB) * 64 + c0] = r2;
        }
    }
}

// ---------------------------------------------------------------------------
// Fallback (tiny ws): atomic scatter at 64 ch + in-place transform.
// ---------------------------------------------------------------------------
__global__ __launch_bounds__(256) void scatter64_kernel(
    const float* __restrict__ x, const float* __restrict__ vals,
    const int* __restrict__ rows, const int* __restrict__ cols,
    float* __restrict__ out, int E)
{
    int idx = blockIdx.x * 256 + threadIdx.x;
    if (idx >= E * 256) return;
    int c = idx & 63, b = (idx >> 6) & 3, e = idx >> 8;
    atomicAdd(&out[((size_t)b * N_ + rows[e]) * 64 + c],
              vals[e] * x[((size_t)b * N_ + cols[e]) * 64 + c]);
}

__global__ __launch_bounds__(256) void transform_inplace_kernel(
    const float* __restrict__ x,
    const float* __restrict__ Wlin, const float* __restrict__ blin,
    const float* __restrict__ Weye, const float* __restrict__ beye,
    float* __restrict__ out, int total_nodes)
{
    __shared__ float Wt[64 * 65];
    __shared__ float bias[64];
    __shared__ float axs[4][64];
    __shared__ float xs2[4][64];
    int tid = threadIdx.x;
    for (int i = tid; i < HALF_ * CIN_; i += 256) {
        int o = i >> 6, c = i & 63;
        Wt[c * 65 + o]      = Wlin[i];
        Wt[c * 65 + o + 32] = Weye[i];
    }
    if (tid < 32) { bias[tid] = blin[tid]; bias[tid + 32] = beye[tid]; }
    __syncthreads();
    int wave = tid >> 6, lane = tid & 63;
    int node = blockIdx.x * 4 + wave;
    if (node < total_nodes) {
        axs[wave][lane] = out[node * 64 + lane];
        xs2[wave][lane] = x[node * 64 + lane];
    }
    __syncthreads();
    if (node >= total_nodes) return;
    const float* src = (lane < 32) ? axs[wave] : xs2[wave];
    float acc = bias[lane];
#pragma unroll
    for (int c = 0; c < 64; ++c) acc = fmaf(src[c], Wt[c * 65 + lane], acc);
    out[node * 64 + lane] = acc;
}

extern "C" void kernel_launch(void* const* d_in, const int* in_sizes, int n_in,
                              void* d_out, int out_size, void* d_ws, size_t ws_size,
                              hipStream_t stream) {
    const float* x    = (const float*)d_in[0];
    const float* vals = (const float*)d_in[1];
    const float* Wlin = (const float*)d_in[2];
    const float* blin = (const float*)d_in[3];
    const float* Weye = (const float*)d_in[4];
    const float* beye = (const float*)d_in[5];
    const int*   rows = (const int*)d_in[6];
    const int*   cols = (const int*)d_in[7];
    float*       out  = (float*)d_out;

    const int E = in_sizes[1];                       // 800000
    const int total_nodes = B_ * N_;                 // 200000

    // ws layout
    char* base = (char*)d_ws;
    size_t off_y      = 0;
    size_t off_edge1  = off_y     + (size_t)N_ * B_ * HALF_ * 2;   // 12.8 MB
    size_t off_cur    = off_edge1 + (size_t)SB_ * SCAP_ * 8;       // 9.60 MB
    size_t need       = off_cur   + 8192;

    if (ws_size >= need && E <= NFB_ * FILL_T) {
        unsigned short* y      = (unsigned short*)(base + off_y);
        int2*           sEdge1 = (int2*)          (base + off_edge1);
        int*            cbcur  = (int*)           (base + off_cur);

        hipMemsetAsync(cbcur, 0, SB_ * 4, stream);
        mega1_kernel<<<TBLK_ + NFB_, 256, 0, stream>>>(
            x, Wlin, Weye, beye, y, out, rows, cols, vals, cbcur, sEdge1, E);
        sortgather_kernel<<<SB_, 256, 0, stream>>>(
            sEdge1, cbcur, (const unsigned int*)y, blin, out);
    } else {
        hipMemsetAsync(d_out, 0, (size_t)out_size * sizeof(float), stream);
        scatter64_kernel<<<(E * 256 + 255) / 256, 256, 0, stream>>>(
            x, vals, rows, cols, out, E);
        transform_inplace_kernel<<<(total_nodes + 3) / 4, 256, 0, stream>>>(
            x, Wlin, blin, Weye, beye, out, total_nodes);
    }
}

// Round 7
// 172.435 us; speedup vs baseline: 1.0608x; 1.0509x over previous
//
#include <hip/hip_runtime.h>
#include <hip/hip_bf16.h>

// Problem constants (GCNLayer_13357348290889): B=4, N=50000, CIN=64, HALF=32.
#define B_    4
#define N_    50000
#define CIN_  64
#define HALF_ 32
#define NFB_  196      // fill blocks: ceil(E / FILL_T)
#define FILL_T 4096    // edges per fill block
#define SB_   1563     // sort buckets of 32 rows: fb = row >> 5
#define SCAP_ 768      // records per bucket (mean 512, sd 23 -> +11 sigma)
#define TBLK_ 1563     // transform blocks (200000 nodes / 128)
#define XCH_  2176     // x-tile 16B chunks: 128 rows * 17 (stride-68-float pad)
#define WCH_  1088     // W 16B chunks: 64 rows * 17

typedef __attribute__((ext_vector_type(8))) short bf16x8;   // MFMA A/B frag
typedef __attribute__((ext_vector_type(4))) float f32x4;    // MFMA C/D frag

// fp32 -> bf16 round-to-nearest-even (inputs are finite normals)
static __device__ __forceinline__ unsigned short f2bf(float f) {
    unsigned u = __float_as_uint(f);
    return (unsigned short)((u + 0x7FFFu + ((u >> 16) & 1u)) >> 16);
}

// pack 8 consecutive f32 -> bf16x8 (RNE via v_cvt_pk_bf16_f32)
static __device__ __forceinline__ bf16x8 pack8(float4 a, float4 b) {
    union { __hip_bfloat162 h[4]; bf16x8 v; } u;
    u.h[0] = __float22bfloat162_rn(make_float2(a.x, a.y));
    u.h[1] = __float22bfloat162_rn(make_float2(a.z, a.w));
    u.h[2] = __float22bfloat162_rn(make_float2(b.x, b.y));
    u.h[3] = __float22bfloat162_rn(make_float2(b.z, b.w));
    return u.v;
}

// async 16B global -> LDS (dest = wave-uniform base + lane*16; gsrc per-lane)
static __device__ __forceinline__ void gload_lds16(const float* g, float* l) {
    __builtin_amdgcn_global_load_lds(
        (const __attribute__((address_space(1))) void*)g,
        (__attribute__((address_space(3))) void*)l, 16, 0, 0);
}

// ---------------------------------------------------------------------------
// mega1: grid-fused transform (blocks NFB_..) + fill (blocks 0..195).
//
// R7 = R6 hardened (R6 bench died; only risky idiom was break-in-unroll
// around async LDS-DMA -> replaced with pure if-guards, chunk distribution
// idx = wv + 4*k). Design rationale (R5 post-mortem): register staging is
// compiler-serialized (VGPR=52, ~24 HBM latencies per wave critical path);
// global_load_lds width=16 is fire-and-forget, zero VGPR, one vmcnt drain
// at the block barrier.
// LDS row stride = 17 chunks (68 floats): conflict-free ds_read_b128
// (2-way max); pad works with global_load_lds because the GLOBAL source
// addr is per-lane (lane maps P -> row=P/17, chunk=P%17; pad chunk stages
// a duplicate of chunk 15, never read back).
// MFMA D = W · X^T (verified R4/R5): col=lane&15 -> node,
// row=(lane>>4)*4+reg -> 4 consecutive out channels per lane.
// ---------------------------------------------------------------------------
struct TrS  { float xs[XCH_ * 4]; float ws[WCH_ * 4]; };   // 34.8KB + 17.4KB
union SMemU { int hist[SB_]; TrS tr; };                    // 52224 B

__global__ __launch_bounds__(256) void mega1_kernel(
    const float* __restrict__ x,
    const float* __restrict__ Wlin,
    const float* __restrict__ Weye, const float* __restrict__ beye,
    unsigned short* __restrict__ y, float* __restrict__ out,
    const int* __restrict__ rows, const int* __restrict__ cols,
    const float* __restrict__ vals,
    int* __restrict__ cbcursor, int2* __restrict__ sEdge1, int E)
{
    __shared__ __align__(16) SMemU sm;
    int t = threadIdx.x;

    if (blockIdx.x < NFB_) {
        // ---------------- fill part ----------------
        for (int i = t; i < SB_; i += 256) sm.hist[i] = 0;
        __syncthreads();

        int e0   = blockIdx.x * FILL_T;
        int eEnd = e0 + FILL_T; if (eEnd > E) eEnd = E;

        for (int e = e0 + t; e < eEnd; e += 256)
            atomicAdd(&sm.hist[((unsigned)rows[e]) >> 5], 1);
        __syncthreads();

        // exchange: hist[i] becomes this block's global base for bucket i
        for (int i = t; i < SB_; i += 256) {
            int h = sm.hist[i];
            if (h) sm.hist[i] = atomicAdd(&cbcursor[i], h);
        }
        __syncthreads();

        for (int e = e0 + t; e < eEnd; e += 256) {
            unsigned r = (unsigned)rows[e];
            int fb = r >> 5;
            int p  = atomicAdd(&sm.hist[fb], 1);   // global slot directly
            if (p < SCAP_)
                sEdge1[(size_t)fb * SCAP_ + p] =
                    make_int2((int)(((unsigned)cols[e]) | (r << 16)),
                              __float_as_int(vals[e]));
        }
        return;
    }

    // ---------------- transform part (MFMA, LDS-staged) ----------------
    int tb   = blockIdx.x - NFB_;                  // 0..1562
    int wv   = t >> 6, lane = t & 63;
    int lm   = lane & 15;                          // node-in-mtile / W-row
    int lg   = lane >> 4;                          // k-chunk 0..3
    int nodeB = tb * 128;

    // bias (independent tiny loads, issue before staging barrier)
    float4 be0 = ((const float4*)beye)[lg];        // otile 2 bias (4 ch)
    float4 be1 = ((const float4*)beye)[4 + lg];    // otile 3 bias

    // ---- stage x-tile: 34 chunk-groups of 1KB (idx = wv + 4k, k<9) ----
#pragma unroll
    for (int k = 0; k < 9; ++k) {
        int idx = wv + 4 * k;
        if (idx < (XCH_ / 64)) {
            int P   = idx * 64 + lane;             // chunk position
            unsigned row = (unsigned)P / 17u;
            int p   = P - (int)row * 17;
            if (p > 15) p = 15;                    // pad chunk: harmless dup
            int grow = nodeB + (int)row;
            if (grow > B_ * N_ - 1) grow = B_ * N_ - 1;
            gload_lds16(x + (size_t)grow * 64 + p * 4,
                        sm.tr.xs + (size_t)idx * 256);
        }
    }
    // ---- stage W (Wlin rows 0-31, Weye rows 32-63): 17 chunk-groups ----
#pragma unroll
    for (int k = 0; k < 5; ++k) {
        int idx = wv + 4 * k;
        if (idx < (WCH_ / 64)) {
            int P   = idx * 64 + lane;
            unsigned row = (unsigned)P / 17u;
            int p   = P - (int)row * 17;
            if (p > 15) p = 15;
            const float* wsrc = (row < 32) ? (Wlin + row * 64)
                                           : (Weye + (row - 32) * 64);
            gload_lds16(wsrc + p * 4, sm.tr.ws + (size_t)idx * 256);
        }
    }
    __syncthreads();                               // vmcnt(0) drain + barrier

    // ---- fragments from LDS (2-way max bank aliasing: free) ----
    const float4* x4 = (const float4*)sm.tr.xs;
    const float4* w4 = (const float4*)sm.tr.ws;

    bf16x8 xf[2][2];
#pragma unroll
    for (int m = 0; m < 2; ++m) {
        int row  = wv * 32 + m * 16 + lm;
        int base = row * 17;
        xf[m][0] = pack8(x4[base + 2 * lg],     x4[base + 2 * lg + 1]);
        xf[m][1] = pack8(x4[base + 8 + 2 * lg], x4[base + 9 + 2 * lg]);
    }
    bf16x8 wf[8];
#pragma unroll
    for (int u = 0; u < 4; ++u) {
        int base = (u * 16 + lm) * 17;
        wf[u * 2 + 0] = pack8(w4[base + 2 * lg],     w4[base + 2 * lg + 1]);
        wf[u * 2 + 1] = pack8(w4[base + 8 + 2 * lg], w4[base + 9 + 2 * lg]);
    }

    // ---- MFMA + stores ----
    ushort4* y4   = (ushort4*)y;
    float4*  out4 = (float4*)out;
#pragma unroll
    for (int m = 0; m < 2; ++m) {
        int node0 = nodeB + wv * 32 + m * 16;
        if (node0 < B_ * N_) {
            int flat = node0 + lm;                 // this lane's output node
            int b    = flat / N_;
            int nn   = flat - b * N_;
#pragma unroll
            for (int u = 0; u < 4; ++u) {
                f32x4 acc = {0.f, 0.f, 0.f, 0.f};
                acc = __builtin_amdgcn_mfma_f32_16x16x32_bf16(wf[u*2+0], xf[m][0], acc, 0, 0, 0);
                acc = __builtin_amdgcn_mfma_f32_16x16x32_bf16(wf[u*2+1], xf[m][1], acc, 0, 0, 0);
                if (u < 2) {                       // lin -> y bf16 [n][b][32]
                    ushort4 pk;
                    pk.x = f2bf(acc[0]); pk.y = f2bf(acc[1]);
                    pk.z = f2bf(acc[2]); pk.w = f2bf(acc[3]);
                    y4[(size_t)nn * 32 + b * 8 + u * 4 + lg] = pk;
                } else {                           // eye -> out[:,32:64] + bias
                    float4 be = (u == 2) ? be0 : be1;
                    out4[(size_t)flat * 16 + 8 + (u - 2) * 4 + lg] =
                        make_float4(acc[0] + be.x, acc[1] + be.y,
                                    acc[2] + be.z, acc[3] + be.w);
                }
            }
        }
    }
}

// ---------------------------------------------------------------------------
// sortgather: one 256-thread block (4 waves) per 32-row bucket.
// Phase A: cache <=3 records/thread in registers + LDS row histogram.
// Phase B: 32-bin shfl scan. Phase C: scatter 4B records into LDS.
// Phase D: readfirstlane-scalarized records, full-group/clamped-tail split,
// two rows in flight per wave. out[b,n,0:32] = b_lin + sum. No f32 atomics.
// ---------------------------------------------------------------------------
#define GRP(J, EN, CLAMP, A0, A1) do {                                     \
        unsigned rec_[8];                                                  \
        _Pragma("unroll")                                                  \
        for (int u_ = 0; u_ < 8; ++u_) {                                   \
            int idx_ = (J) + u_;                                           \
            unsigned rr_;                                                  \
            if (CLAMP) {                                                   \
                rr_ = sorted[idx_ < (EN) ? idx_ : (EN) - 1];               \
                if (idx_ >= (EN)) rr_ &= 0xFFFFu;  /* zero val: no-op */   \
            } else {                                                       \
                rr_ = sorted[idx_];                                        \
            }                                                              \
            rec_[u_] = __builtin_amdgcn_readfirstlane(rr_);                \
        }                                                                  \
        unsigned w4_[8];                                                   \
        _Pragma("unroll")                                                  \
        for (int u_ = 0; u_ < 8; ++u_)                                     \
            w4_[u_] = yu[(size_t)(rec_[u_] & 0xFFFFu) * 64 + lane];        \
        _Pragma("unroll")                                                  \
        for (int u_ = 0; u_ < 8; ++u_) {                                   \
            float vv_ = __uint_as_float(rec_[u_] & 0xFFFF0000u);           \
            A0 = fmaf(vv_, __uint_as_float(w4_[u_] << 16), A0);            \
            A1 = fmaf(vv_, __uint_as_float(w4_[u_] & 0xFFFF0000u), A1);    \
        }                                                                  \
    } while (0)

__global__ __launch_bounds__(256) void sortgather_kernel(
    const int2* __restrict__ sEdge1, const int* __restrict__ cbcursor,
    const unsigned int* __restrict__ yu, const float* __restrict__ blin,
    float* __restrict__ out)
{
    __shared__ int hist[32], cur[32], rs_s[32], rs_e[32];
    __shared__ unsigned int sorted[SCAP_];         // 3 KB

    int t = threadIdx.x, fb = blockIdx.x;
    int cnt = cbcursor[fb]; if (cnt > SCAP_) cnt = SCAP_;
    const int2* src = sEdge1 + (size_t)fb * SCAP_;

    if (t < 32) hist[t] = 0;
    __syncthreads();

    // Phase A: register-cache records (static indexing) + histogram
    int2 rc[3];
#pragma unroll
    for (int u = 0; u < 3; ++u) {
        int i = t + 256 * u;
        if (i < cnt) {
            rc[u] = src[i];
            atomicAdd(&hist[(((unsigned)rc[u].x) >> 16) & 31u], 1);
        }
    }
    __syncthreads();

    // Phase B: 32-bin inclusive scan in wave 0 (5 shfl steps)
    if (t < 32) {
        int v = hist[t], s = v;
#pragma unroll
        for (int d = 1; d < 32; d <<= 1) {
            int tv = __shfl_up(s, d, 64);
            if (t >= d) s += tv;
        }
        cur[t] = s - v; rs_s[t] = s - v; rs_e[t] = s;
    }
    __syncthreads();

    // Phase C: scatter from registers into row-grouped LDS
#pragma unroll
    for (int u = 0; u < 3; ++u) {
        int i = t + 256 * u;
        if (i < cnt) {
            int2 w = rc[u];
            int rl = (((unsigned)w.x) >> 16) & 31;
            int p  = atomicAdd(&cur[rl], 1);
            sorted[p] = ((unsigned)f2bf(__int_as_float(w.y)) << 16)
                      | (((unsigned)w.x) & 0xFFFFu);
        }
    }
    __syncthreads();

    // Phase D: gather, two rows in flight per wave
    int wv = t >> 6, lane = t & 63;
    int b  = lane >> 4;
    int c0 = (lane & 15) * 2;
    float bl0 = blin[c0], bl1 = blin[c0 + 1];

    for (int rp = 0; rp < 4; ++rp) {
        int rA = wv * 8 + rp * 2, rB = rA + 1;
        int stA = rs_s[rA], enA = rs_e[rA];
        int stB = rs_s[rB], enB = rs_e[rB];
        int fA = stA + ((enA - stA) & ~7);
        int fB = stB + ((enB - stB) & ~7);
        float a0A = 0.f, a1A = 0.f, a0B = 0.f, a1B = 0.f;
        int jA = stA, jB = stB;
        while (jA < fA && jB < fB) {               // dual-row: 16 loads in flight
            GRP(jA, enA, false, a0A, a1A); jA += 8;
            GRP(jB, enB, false, a0B, a1B); jB += 8;
        }
        while (jA < fA) { GRP(jA, enA, false, a0A, a1A); jA += 8; }
        while (jB < fB) { GRP(jB, enB, false, a0B, a1B); jB += 8; }
        if (jA < enA) GRP(jA, enA, true, a0A, a1A);
        if (jB < enB) GRP(jB, enB, true, a0B, a1B);

        int nA = fb * 32 + rA, nB = fb * 32 + rB;
        if (nA < N_) {
            float2 r2; r2.x = bl0 + a0A; r2.y = bl1 + a1A;
            *(float2*)&out[((size_t)b * N_ + nA) * 64 + c0] = r2;
        }
        if (nB < N_) {
            float2 r2; r2.x = bl0 + a0B; r2.y = bl1 + a1B;
            *(float2*)&out[((size_t)b * N_ + nB) * 64 + c0] = r2;
        }
    }
}

// ---------------------------------------------------------------------------
// Fallback (tiny ws): atomic scatter at 64 ch + in-place transform.
// ---------------------------------------------------------------------------
__global__ __launch_bounds__(256) void scatter64_kernel(
    const float* __restrict__ x, const float* __restrict__ vals,
    const int* __restrict__ rows, const int* __restrict__ cols,
    float* __restrict__ out, int E)
{
    int idx = blockIdx.x * 256 + threadIdx.x;
    if (idx >= E * 256) return;
    int c = idx & 63, b = (idx >> 6) & 3, e = idx >> 8;
    atomicAdd(&out[((size_t)b * N_ + rows[e]) * 64 + c],
              vals[e] * x[((size_t)b * N_ + cols[e]) * 64 + c]);
}

__global__ __launch_bounds__(256) void transform_inplace_kernel(
    const float* __restrict__ x,
    const float* __restrict__ Wlin, const float* __restrict__ blin,
    const float* __restrict__ Weye, const float* __restrict__ beye,
    float* __restrict__ out, int total_nodes)
{
    __shared__ float Wt[64 * 65];
    __shared__ float bias[64];
    __shared__ float axs[4][64];
    __shared__ float xs2[4][64];
    int tid = threadIdx.x;
    for (int i = tid; i < HALF_ * CIN_; i += 256) {
        int o = i >> 6, c = i & 63;
        Wt[c * 65 + o]      = Wlin[i];
        Wt[c * 65 + o + 32] = Weye[i];
    }
    if (tid < 32) { bias[tid] = blin[tid]; bias[tid + 32] = beye[tid]; }
    __syncthreads();
    int wave = tid >> 6, lane = tid & 63;
    int node = blockIdx.x * 4 + wave;
    if (node < total_nodes) {
        axs[wave][lane] = out[node * 64 + lane];
        xs2[wave][lane] = x[node * 64 + lane];
    }
    __syncthreads();
    if (node >= total_nodes) return;
    const float* src = (lane < 32) ? axs[wave] : xs2[wave];
    float acc = bias[lane];
#pragma unroll
    for (int c = 0; c < 64; ++c) acc = fmaf(src[c], Wt[c * 65 + lane], acc);
    out[node * 64 + lane] = acc;
}

extern "C" void kernel_launch(void* const* d_in, const int* in_sizes, int n_in,
                              void* d_out, int out_size, void* d_ws, size_t ws_size,
                              hipStream_t stream) {
    const float* x    = (const float*)d_in[0];
    const float* vals = (const float*)d_in[1];
    const float* Wlin = (const float*)d_in[2];
    const float* blin = (const float*)d_in[3];
    const float* Weye = (const float*)d_in[4];
    const float* beye = (const float*)d_in[5];
    const int*   rows = (const int*)d_in[6];
    const int*   cols = (const int*)d_in[7];
    float*       out  = (float*)d_out;

    const int E = in_sizes[1];                       // 800000
    const int total_nodes = B_ * N_;                 // 200000

    // ws layout
    char* base = (char*)d_ws;
    size_t off_y      = 0;
    size_t off_edge1  = off_y     + (size_t)N_ * B_ * HALF_ * 2;   // 12.8 MB
    size_t off_cur    = off_edge1 + (size_t)SB_ * SCAP_ * 8;       // 9.60 MB
    size_t need       = off_cur   + 8192;

    if (ws_size >= need && E <= NFB_ * FILL_T) {
        unsigned short* y      = (unsigned short*)(base + off_y);
        int2*           sEdge1 = (int2*)          (base + off_edge1);
        int*            cbcur  = (int*)           (base + off_cur);

        hipMemsetAsync(cbcur, 0, SB_ * 4, stream);
        mega1_kernel<<<TBLK_ + NFB_, 256, 0, stream>>>(
            x, Wlin, Weye, beye, y, out, rows, cols, vals, cbcur, sEdge1, E);
        sortgather_kernel<<<SB_, 256, 0, stream>>>(
            sEdge1, cbcur, (const unsigned int*)y, blin, out);
    } else {
        hipMemsetAsync(d_out, 0, (size_t)out_size * sizeof(float), stream);
        scatter64_kernel<<<(E * 256 + 255) / 256, 256, 0, stream>>>(
            x, vals, rows, cols, out, E);
        transform_inplace_kernel<<<(total_nodes + 3) / 4, 256, 0, stream>>>(
            x, Wlin, blin, Weye, beye, out, total_nodes);
    }
}